// Round 8
// baseline (110.232 us; speedup 1.0000x reference)
//
#include <hip/hip_runtime.h>
#include <hip/hip_bf16.h>

#define NB 8
#define SS 4096
#define DD 1024
#define NI 4094
#define NT 32       // K-steps (BK=32)
#define BK 32

typedef __attribute__((ext_vector_type(8))) short short8;
typedef __attribute__((ext_vector_type(4))) float f32x4;

// ---- ws layout (bytes) ----
#define WB_OFF 0                           // Wb bf16 [1024][1024] swizzled   (2 MB)
#define XB_OFF (2*1024*1024)               // xb bf16 [8][4096][1024] swizzled(64 MB)
#define YB_OFF (XB_OFF + NB*SS*DD*2)       // ybnd bf16 [8][16][4][1024]      (1 MB)
#define PN_OFF (YB_OFF + NB*16*4*1024*2)   // pn f32 [8][4096][4]
#define PC_OFF (PN_OFF + NB*SS*4*4)        // pc f32 [8][4096][4]

// Swizzle (4-slot, as r5): within each 32-elem k-group (4 x 16B slots),
// logical slot s of row r stored at physical slot s ^ ((r>>1)&3).
// Baked into converters; gemm gload_lds stays LINEAR; ds_read same XOR.

__device__ __forceinline__ unsigned short f2bf(float f) {
    union { float f; unsigned int u; } v; v.f = f;
    unsigned int r = v.u + 0x7FFFu + ((v.u >> 16) & 1u);   // RNE
    return (unsigned short)(r >> 16);
}
__device__ __forceinline__ float bf2f(unsigned short u) {
    union { unsigned int u; float f; } v; v.u = ((unsigned int)u) << 16;
    return v.f;
}

// ---- pass 0: x and W -> bf16, 4-slot swizzled, one launch ----
__global__ void conv_all(const float* __restrict__ x, const float* __restrict__ W,
                         unsigned short* __restrict__ xb, unsigned short* __restrict__ Wb) {
    int bid = blockIdx.x;
    const float* src; unsigned short* dst; int tid;
    if (bid < 16384) { src = x; dst = xb; tid = bid * 256 + threadIdx.x; }
    else             { src = W; dst = Wb; tid = (bid - 16384) * 256 + threadIdx.x; }
    int row = tid >> 7;
    int sl  = tid & 127;
    int k0  = (sl >> 2) * 32;
    int s   = sl & 3;
    const float* p = src + (size_t)row * DD + k0 + s * 8;
    float4 a0 = *(const float4*)p;
    float4 a1 = *(const float4*)(p + 4);
    ushort4 o0, o1;
    o0.x = f2bf(a0.x); o0.y = f2bf(a0.y); o0.z = f2bf(a0.z); o0.w = f2bf(a0.w);
    o1.x = f2bf(a1.x); o1.y = f2bf(a1.y); o1.z = f2bf(a1.z); o1.w = f2bf(a1.w);
    unsigned short* q = dst + (size_t)row * DD + k0 + ((s ^ ((row >> 1) & 3)) << 3);
    *(ushort4*)q = o0;
    *(ushort4*)(q + 4) = o1;
}

// ---- pass 1: GEMM C = xb @ Wb^T, 256x256 tile, BK=32, 8 waves (2Mx4N),
//      4 x 32KB LDS buffers, stage-3-ahead, counted vmcnt(4), frag-set
//      double-buffer, FULLY UNROLLED with literal offsets (zero loop
//      address VALU). Fused adjacent-row-diff epilogue.
__launch_bounds__(512, 2)
__global__ void gemm_nc(const unsigned short* __restrict__ xb,
                        const unsigned short* __restrict__ Wb,
                        float* __restrict__ pn, float* __restrict__ pc,
                        unsigned short* __restrict__ ybnd) {
    __shared__ __align__(16) char smem[131072];   // 4 bufs x (A 16K @0 + B 16K @16384)

    const int bid = blockIdx.x;
    const int vb  = (bid & 7) * 64 + (bid >> 3);   // XCD-chunk swizzle
    const int mg  = vb >> 2, bn = vb & 3;
    const int b   = mg >> 4, mt = mg & 15;
    const int m0  = mt * 256;

    const int t = threadIdx.x;
    const int lane = t & 63, w = t >> 6;
    const int wr = w >> 2, wc = w & 3;             // 2(M) x 4(N) waves
    const int lrow = lane & 15, lgrp = lane >> 4;
    const int swo = (((lrow >> 1) & 3) ^ lgrp) << 4;

    const unsigned short* Abase = xb + ((size_t)b * SS + m0) * DD;
    const unsigned short* Bbase = Wb + (size_t)bn * 256 * DD;

    // staging geometry: 4 loads/thread; row sr0 (+128); 16B slot lane&3
    const int sr0 = w * 16 + (lane >> 2);
    const int scb = ((lane & 3) ^ ((sr0 >> 1) & 3)) * 8;   // swizzled col (elems)

    const unsigned short* gA0 = Abase + (size_t)sr0 * DD + scb;
    const unsigned short* gA1 = Abase + (size_t)(sr0 + 128) * DD + scb;
    const unsigned short* gB0 = Bbase + (size_t)sr0 * DD + scb;
    const unsigned short* gB1 = Bbase + (size_t)(sr0 + 128) * DD + scb;

    // per-thread LDS frag bases (wr/wc folded in); all reads = base + literal
    const char* baseAl = smem + wr * 8192 + lrow * 64 + swo;
    const char* baseAh = baseAl + 65536;
    const char* baseBl = smem + 16384 + wc * 4096 + lrow * 64 + swo;
    const char* baseBh = baseBl + 65536;

    // wave-uniform LDS staging dests
    char* const sd = smem + w * 1024;

    f32x4 acc[8][4] = {};
    short8 afA[8], bfA[4], afB[8], bfB[4];

#define GL16(G, L, OFF) __builtin_amdgcn_global_load_lds( \
        (const __attribute__((address_space(1))) void*)(G), \
        (__attribute__((address_space(3))) void*)(L), 16, (OFF), 0)

#define STAGE(KT) do { \
        GL16(gA0, sd + ((KT)&3)*32768,          (KT)*64); \
        GL16(gA1, sd + ((KT)&3)*32768 + 8192,   (KT)*64); \
        GL16(gB0, sd + ((KT)&3)*32768 + 16384,  (KT)*64); \
        GL16(gB1, sd + ((KT)&3)*32768 + 24576,  (KT)*64); \
    } while (0)

#define READF(KT, AF, BF) do { \
        const char* _ba = (((KT)&2) ? baseAh : baseAl) + ((KT)&1)*32768; \
        const char* _bb = (((KT)&2) ? baseBh : baseBl) + ((KT)&1)*32768; \
        _Pragma("unroll") \
        for (int _m = 0; _m < 8; ++_m) AF[_m] = *(const short8*)(_ba + _m*1024); \
        _Pragma("unroll") \
        for (int _n = 0; _n < 4; ++_n) BF[_n] = *(const short8*)(_bb + _n*1024); \
    } while (0)

#define MFMA32(AF, BF) do { \
        __builtin_amdgcn_s_setprio(1); \
        _Pragma("unroll") \
        for (int _m = 0; _m < 8; ++_m) \
            _Pragma("unroll") \
            for (int _n = 0; _n < 4; ++_n) \
                acc[_m][_n] = __builtin_amdgcn_mfma_f32_16x16x32_bf16( \
                    AF[_m], BF[_n], acc[_m][_n], 0, 0, 0); \
        __builtin_amdgcn_s_setprio(0); \
    } while (0)

#define ITER(KT, AFc, BFc, AFn, BFn) do { \
        if ((KT) < NT - 3) STAGE((KT) + 3); \
        if ((KT) < NT - 1) READF((KT) + 1, AFn, BFn); \
        MFMA32(AFc, BFc); \
        if ((KT) < NT - 3) { asm volatile("s_waitcnt vmcnt(4) lgkmcnt(0)" ::: "memory"); } \
        else               { asm volatile("s_waitcnt vmcnt(0) lgkmcnt(0)" ::: "memory"); } \
        __builtin_amdgcn_s_barrier(); \
    } while (0)

    STAGE(0); STAGE(1); STAGE(2);
    asm volatile("s_waitcnt vmcnt(4)" ::: "memory");   // stages 0,1 landed
    __builtin_amdgcn_s_barrier();
    READF(0, afA, bfA);

    ITER(0,  afA, bfA, afB, bfB);  ITER(1,  afB, bfB, afA, bfA);
    ITER(2,  afA, bfA, afB, bfB);  ITER(3,  afB, bfB, afA, bfA);
    ITER(4,  afA, bfA, afB, bfB);  ITER(5,  afB, bfB, afA, bfA);
    ITER(6,  afA, bfA, afB, bfB);  ITER(7,  afB, bfB, afA, bfA);
    ITER(8,  afA, bfA, afB, bfB);  ITER(9,  afB, bfB, afA, bfA);
    ITER(10, afA, bfA, afB, bfB);  ITER(11, afB, bfB, afA, bfA);
    ITER(12, afA, bfA, afB, bfB);  ITER(13, afB, bfB, afA, bfA);
    ITER(14, afA, bfA, afB, bfB);  ITER(15, afB, bfB, afA, bfA);
    ITER(16, afA, bfA, afB, bfB);  ITER(17, afB, bfB, afA, bfA);
    ITER(18, afA, bfA, afB, bfB);  ITER(19, afB, bfB, afA, bfA);
    ITER(20, afA, bfA, afB, bfB);  ITER(21, afB, bfB, afA, bfA);
    ITER(22, afA, bfA, afB, bfB);  ITER(23, afB, bfB, afA, bfA);
    ITER(24, afA, bfA, afB, bfB);  ITER(25, afB, bfB, afA, bfA);
    ITER(26, afA, bfA, afB, bfB);  ITER(27, afB, bfB, afA, bfA);
    ITER(28, afA, bfA, afB, bfB);  ITER(29, afB, bfB, afA, bfA);
    ITER(30, afA, bfA, afB, bfB);  ITER(31, afB, bfB, afA, bfA);

    // ---------------- epilogue ----------------
    unsigned short* Y = (unsigned short*)smem;
    const int YP = 264;   // padded cols

    // chunk A: C rows 0..129
    if (wr == 0) {
        #pragma unroll
        for (int m = 0; m < 8; ++m) {
            int rbase = m * 16 + lgrp * 4;
            #pragma unroll
            for (int n = 0; n < 4; ++n) {
                int col = wc * 64 + n * 16 + lrow;
                #pragma unroll
                for (int j = 0; j < 4; ++j)
                    Y[(rbase + j) * YP + col] = f2bf(acc[m][n][j]);
            }
        }
    } else if (lgrp == 0) {   // rows 128,129 from wr=1, m=0, j=0,1
        #pragma unroll
        for (int n = 0; n < 4; ++n) {
            int col = wc * 64 + n * 16 + lrow;
            #pragma unroll
            for (int j = 0; j < 2; ++j)
                Y[(128 + j) * YP + col] = f2bf(acc[0][n][j]);
        }
    }
    __syncthreads();

    // dump C rows 0,1 (slots 0,1)
    if (t < 256) {
        int rr = t >> 7, cc = (t & 127) * 2;
        ushort2 v;
        v.x = Y[rr * YP + cc]; v.y = Y[rr * YP + cc + 1];
        *(ushort2*)(ybnd + ((size_t)((b * 16 + mt) * 4 + rr)) * 1024 + bn * 256 + cc) = v;
    }
    // reduce rows 0..127
    {
        int r = t >> 2, q = t & 3;
        const unsigned short* y0 = Y + r * YP + q * 64;
        float sn = 0.f, sc = 0.f;
        #pragma unroll
        for (int c8 = 0; c8 < 8; ++c8) {
            short8 v0 = *(const short8*)(y0 + c8 * 8);
            short8 v1 = *(const short8*)(y0 + YP + c8 * 8);
            short8 v2 = *(const short8*)(y0 + 2 * YP + c8 * 8);
            #pragma unroll
            for (int j = 0; j < 8; ++j) {
                float f0 = bf2f((unsigned short)v0[j]);
                float f1 = bf2f((unsigned short)v1[j]);
                float f2 = bf2f((unsigned short)v2[j]);
                float d0 = f1 - f0, d1 = f2 - f1;
                sn += d0 * d0; sc += d0 * d1;
            }
        }
        sn += __shfl_xor(sn, 1); sn += __shfl_xor(sn, 2);
        sc += __shfl_xor(sc, 1); sc += __shfl_xor(sc, 2);
        if (q == 0) {
            size_t o = ((size_t)b * SS + m0 + r) * 4 + bn;
            pn[o] = sn; pc[o] = sc;
        }
    }
    __syncthreads();

    // chunk B: C rows 128..255 -> LDS rows 0..127
    if (wr == 1) {
        #pragma unroll
        for (int m = 0; m < 8; ++m) {
            int rbase = m * 16 + lgrp * 4;
            #pragma unroll
            for (int n = 0; n < 4; ++n) {
                int col = wc * 64 + n * 16 + lrow;
                #pragma unroll
                for (int j = 0; j < 4; ++j)
                    Y[(rbase + j) * YP + col] = f2bf(acc[m][n][j]);
            }
        }
    }
    __syncthreads();

    // dump C rows 254,255 (LDS rows 126,127 -> slots 2,3)
    if (t < 256) {
        int rr = t >> 7, cc = (t & 127) * 2;
        ushort2 v;
        v.x = Y[(126 + rr) * YP + cc]; v.y = Y[(126 + rr) * YP + cc + 1];
        *(ushort2*)(ybnd + ((size_t)((b * 16 + mt) * 4 + 2 + rr)) * 1024 + bn * 256 + cc) = v;
    }
    // reduce rows 128..254
    {
        int r2 = t >> 2, q = t & 3;
        float sn = 0.f, sc = 0.f;
        if (r2 <= 126) {
            const unsigned short* y0 = Y + r2 * YP + q * 64;
            int rc = (r2 < 126) ? 2 : 1;
            #pragma unroll
            for (int c8 = 0; c8 < 8; ++c8) {
                short8 v0 = *(const short8*)(y0 + c8 * 8);
                short8 v1 = *(const short8*)(y0 + YP + c8 * 8);
                short8 v2 = *(const short8*)(y0 + rc * YP + c8 * 8);
                #pragma unroll
                for (int j = 0; j < 8; ++j) {
                    float f0 = bf2f((unsigned short)v0[j]);
                    float f1 = bf2f((unsigned short)v1[j]);
                    float f2 = bf2f((unsigned short)v2[j]);
                    float d0 = f1 - f0, d1 = f2 - f1;
                    sn += d0 * d0; sc += d0 * d1;
                }
            }
        }
        sn += __shfl_xor(sn, 1); sn += __shfl_xor(sn, 2);
        sc += __shfl_xor(sc, 1); sc += __shfl_xor(sc, 2);
        if (q == 0 && r2 <= 126) {
            size_t o = ((size_t)b * SS + m0 + 128 + r2) * 4 + bn;
            pn[o] = sn;
            if (r2 <= 125) pc[o] = sc;
        }
    }
}

// ---- pass 2: cross-tile boundary scores from dumped rows ----
__global__ void bnd_k(const unsigned short* __restrict__ ybnd,
                      float* __restrict__ pn, float* __restrict__ pc) {
    int b = blockIdx.x / 15, mt = blockIdx.x % 15;
    const unsigned short* T0 = ybnd + ((size_t)(b * 16 + mt) * 4) * 1024;
    const unsigned short* T1 = T0 + 4 * 1024;
    int l = threadIdx.x;
    float n255 = 0.f, c254 = 0.f, c255 = 0.f;
    #pragma unroll
    for (int k = 0; k < 16; ++k) {
        int c = l * 16 + k;
        float s2 = bf2f(T0[2 * 1024 + c]);
        float s3 = bf2f(T0[3 * 1024 + c]);
        float u0 = bf2f(T1[0 * 1024 + c]);
        float u1 = bf2f(T1[1 * 1024 + c]);
        float d254 = s3 - s2, d255 = u0 - s3, d256 = u1 - u0;
        n255 += d255 * d255; c254 += d254 * d255; c255 += d255 * d256;
    }
    #pragma unroll
    for (int off = 32; off > 0; off >>= 1) {
        n255 += __shfl_down(n255, off);
        c254 += __shfl_down(c254, off);
        c255 += __shfl_down(c255, off);
    }
    if (l == 0) {
        int i255 = mt * 256 + 255;
        float4 vn = {n255, 0.f, 0.f, 0.f};
        float4 va = {c254, 0.f, 0.f, 0.f};
        float4 vb = {c255, 0.f, 0.f, 0.f};
        *(float4*)(pn + ((size_t)b * SS + i255) * 4) = vn;
        *(float4*)(pc + ((size_t)b * SS + i255 - 1) * 4) = va;
        *(float4*)(pc + ((size_t)b * SS + i255) * 4) = vb;
    }
}

// ---- pass 3: combine partials -> scores -> adj ----
__global__ void score_k(const float* __restrict__ pn, const float* __restrict__ pc,
                        const float* __restrict__ gate, float* __restrict__ out) {
    int tid = blockIdx.x * 256 + threadIdx.x;
    if (tid >= NB * NI) return;
    int b = tid / NI;
    int i = tid - b * NI;
    size_t base = ((size_t)b * SS + i) * 4;
    float n0 = 0.f, n1 = 0.f, c0 = 0.f;
    #pragma unroll
    for (int j = 0; j < 4; ++j) {
        n0 += pn[base + j];
        n1 += pn[base + 4 + j];
        c0 += pc[base + j];
    }
    float d1a = sqrtf(fmaxf(n0, 0.f));
    float d1b = sqrtf(fmaxf(n1, 0.f));
    float d2  = sqrtf(fmaxf(n0 + 2.f * c0 + n1, 0.f));
    float s = fmaxf(1.f - (d1a + d1b - d2) / fmaxf(d2, 1e-6f), 0.f);
    float g = gate[0] * 0.5f;
    out[(size_t)b * SS + i + 1] = g * (s * (1.f / (float)NI) - 0.5f) * 0.1f;
    if (i == 0) {
        float e = g * (-0.5f) * 0.1f;
        out[(size_t)b * SS] = e;
        out[(size_t)b * SS + SS - 1] = e;
    }
}

extern "C" void kernel_launch(void* const* d_in, const int* in_sizes, int n_in,
                              void* d_out, int out_size, void* d_ws, size_t ws_size,
                              hipStream_t stream) {
    const float* x    = (const float*)d_in[0];
    const float* W    = (const float*)d_in[1];
    // d_in[2] (bias) cancels in all distances -> unused
    const float* gate = (const float*)d_in[3];
    float* out = (float*)d_out;
    char* ws = (char*)d_ws;

    unsigned short* Wb   = (unsigned short*)(ws + WB_OFF);
    unsigned short* xb   = (unsigned short*)(ws + XB_OFF);
    unsigned short* ybnd = (unsigned short*)(ws + YB_OFF);
    float* pn = (float*)(ws + PN_OFF);
    float* pc = (float*)(ws + PC_OFF);

    conv_all<<<16896, 256, 0, stream>>>(x, W, xb, Wb);
    gemm_nc<<<512, 512, 0, stream>>>(xb, Wb, pn, pc, ybnd);
    bnd_k<<<NB * 15, 64, 0, stream>>>(ybnd, pn, pc);
    score_k<<<(NB * NI + 255) / 256, 256, 0, stream>>>(pn, pc, gate, out);
}

// Round 9
// 102.012 us; speedup vs baseline: 1.0806x; 1.0806x over previous
//
#include <hip/hip_runtime.h>
#include <hip/hip_bf16.h>

#define NB 8
#define SS 4096
#define DD 1024
#define NI 4094
#define NT 32       // K-steps (BK=32)
#define BK 32

typedef __attribute__((ext_vector_type(8))) short short8;
typedef __attribute__((ext_vector_type(4))) float f32x4;

// ---- ws layout (bytes) ----
#define WB_OFF 0                            // Wb fp8 [1024][1024]       (1 MB)
#define XB_OFF (1024*1024)                  // xb fp8 [8*4096][1024]     (32 MB)
#define YB_OFF (XB_OFF + NB*SS*DD)          // ybnd bf16 [8][16][4][1024](1 MB)
#define PN_OFF (YB_OFF + NB*16*4*1024*2)    // pn f32 [8][4096][4]
#define PC_OFF (PN_OFF + NB*SS*4*4)         // pc f32 [8][4096][4]

__device__ __forceinline__ unsigned short f2bf(float f) {
    union { float f; unsigned int u; } v; v.f = f;
    unsigned int r = v.u + 0x7FFFu + ((v.u >> 16) & 1u);   // RNE
    return (unsigned short)(r >> 16);
}
__device__ __forceinline__ float bf2f(unsigned short u) {
    union { unsigned int u; float f; } v; v.u = ((unsigned int)u) << 16;
    return v.f;
}
// float -> OCP e4m3fn, RNE, flush subnormals (data is pre-scaled into normal range)
__device__ __forceinline__ unsigned int f2e4m3(float f) {
    union { float f; unsigned int u; } v; v.f = f;
    unsigned int s = (v.u >> 24) & 0x80u;
    unsigned int r = v.u + 0x7FFFFu + ((v.u >> 20) & 1u);  // RNE at bit 20 (3-bit mantissa)
    int e = (int)((r >> 23) & 0xFFu);
    unsigned int mag = ((unsigned int)(e - 120) << 3) | ((r >> 20) & 7u);
    if (e < 121) mag = 0u;          // subnormal/zero -> 0
    if (e > 134) mag = 0x7Eu;       // clamp (won't trigger for our data)
    return s | mag;
}

// ---- pass 0: x -> fp8 (scale 1), W -> fp8 (scale 16; score is scale-invariant) ----
__global__ void conv_all(const float* __restrict__ x, const float* __restrict__ W,
                         unsigned char* __restrict__ xb, unsigned char* __restrict__ Wb) {
    int bid = blockIdx.x;
    const float* src; unsigned char* dst; int tid; float sc;
    if (bid < 16384) { src = x; dst = xb; tid = bid * 256 + threadIdx.x; sc = 1.0f; }
    else             { src = W; dst = Wb; tid = (bid - 16384) * 256 + threadIdx.x; sc = 16.0f; }
    size_t i = (size_t)tid * 8;
    float4 a0 = *(const float4*)(src + i);
    float4 a1 = *(const float4*)(src + i + 4);
    unsigned int lo = f2e4m3(a0.x * sc) | (f2e4m3(a0.y * sc) << 8) |
                      (f2e4m3(a0.z * sc) << 16) | (f2e4m3(a0.w * sc) << 24);
    unsigned int hi = f2e4m3(a1.x * sc) | (f2e4m3(a1.y * sc) << 8) |
                      (f2e4m3(a1.z * sc) << 16) | (f2e4m3(a1.w * sc) << 24);
    uint2 o; o.x = lo; o.y = hi;
    *(uint2*)(dst + i) = o;
}

// ---- pass 1: GEMM C = xb @ Wb^T (fp8 e4m3 MFMA 16x16x32), 256x256 tile,
//      BK=32, 8 waves (2Mx4N), 4 x 16KB LDS buffers, stage-3-ahead counted
//      vmcnt, frag double-buffer, fully unrolled literal offsets.
//      Linear LDS layout (32B rows are naturally bank-even for b64 reads).
//      Fused adjacent-row-diff epilogue.
__launch_bounds__(512, 2)
__global__ void gemm_nc(const unsigned char* __restrict__ xb,
                        const unsigned char* __restrict__ Wb,
                        float* __restrict__ pn, float* __restrict__ pc,
                        unsigned short* __restrict__ ybnd) {
    __shared__ __align__(16) char smem[69632];   // 4 bufs x (A 8K + B 8K) = 64K; epilogue Y needs 66K

    const int bid = blockIdx.x;
    const int vb  = (bid & 7) * 64 + (bid >> 3);   // XCD-chunk swizzle
    const int mg  = vb >> 2, bn = vb & 3;
    const int b   = mg >> 4, mt = mg & 15;
    const int m0  = mt * 256;

    const int t = threadIdx.x;
    const int lane = t & 63, w = t >> 6;
    const int wr = w >> 2, wc = w & 3;             // 2(M) x 4(N) waves
    const int lrow = lane & 15, lgrp = lane >> 4;

    // global per-lane staging sources (row = w*32 + lane/2, 16B half = lane&1)
    const unsigned char* gA = xb + ((size_t)b * SS + m0 + w * 32 + (lane >> 1)) * DD + (lane & 1) * 16;
    const unsigned char* gB = Wb + ((size_t)bn * 256 + w * 32 + (lane >> 1)) * DD + (lane & 1) * 16;
    // wave-uniform LDS staging dests (lane*16 implicit in gload_lds)
    char* const sdA = smem + w * 1024;
    char* const sdB = smem + 8192 + w * 1024;
    // per-thread LDS frag bases: A row r at byte r*32 + lgrp*8
    const char* baseA = smem + (wr * 128 + lrow) * 32 + lgrp * 8;
    const char* baseB = smem + 8192 + (wc * 64 + lrow) * 32 + lgrp * 8;

    f32x4 acc[8][4] = {};
    long afA[8], bfA[4], afB[8], bfB[4];

#define GL16(G, L, OFF) __builtin_amdgcn_global_load_lds( \
        (const __attribute__((address_space(1))) void*)(G), \
        (__attribute__((address_space(3))) void*)(L), 16, (OFF), 0)

#define STAGE(KT) do { \
        GL16(gA, sdA + ((KT)&3)*16384, (KT)*32); \
        GL16(gB, sdB + ((KT)&3)*16384, (KT)*32); \
    } while (0)

#define READF(KT, AF, BF) do { \
        const char* _a = baseA + ((KT)&3)*16384; \
        const char* _b = baseB + ((KT)&3)*16384; \
        _Pragma("unroll") \
        for (int _m = 0; _m < 8; ++_m) AF[_m] = *(const long*)(_a + _m*512); \
        _Pragma("unroll") \
        for (int _n = 0; _n < 4; ++_n) BF[_n] = *(const long*)(_b + _n*512); \
    } while (0)

#define MFMA32(AF, BF) do { \
        __builtin_amdgcn_s_setprio(1); \
        _Pragma("unroll") \
        for (int _m = 0; _m < 8; ++_m) \
            _Pragma("unroll") \
            for (int _n = 0; _n < 4; ++_n) \
                acc[_m][_n] = __builtin_amdgcn_mfma_f32_16x16x32_fp8_fp8( \
                    AF[_m], BF[_n], acc[_m][_n], 0, 0, 0); \
        __builtin_amdgcn_s_setprio(0); \
    } while (0)

#define ITER(KT, AFc, BFc, AFn, BFn) do { \
        if ((KT) < NT - 3) STAGE((KT) + 3); \
        if ((KT) < NT - 1) READF((KT) + 1, AFn, BFn); \
        MFMA32(AFc, BFc); \
        if ((KT) < NT - 3) { asm volatile("s_waitcnt vmcnt(2) lgkmcnt(0)" ::: "memory"); } \
        else               { asm volatile("s_waitcnt vmcnt(0) lgkmcnt(0)" ::: "memory"); } \
        __builtin_amdgcn_s_barrier(); \
    } while (0)

    STAGE(0); STAGE(1); STAGE(2);
    asm volatile("s_waitcnt vmcnt(2)" ::: "memory");   // K-steps 0,1 landed
    __builtin_amdgcn_s_barrier();
    READF(0, afA, bfA);

    ITER(0,  afA, bfA, afB, bfB);  ITER(1,  afB, bfB, afA, bfA);
    ITER(2,  afA, bfA, afB, bfB);  ITER(3,  afB, bfB, afA, bfA);
    ITER(4,  afA, bfA, afB, bfB);  ITER(5,  afB, bfB, afA, bfA);
    ITER(6,  afA, bfA, afB, bfB);  ITER(7,  afB, bfB, afA, bfA);
    ITER(8,  afA, bfA, afB, bfB);  ITER(9,  afB, bfB, afA, bfA);
    ITER(10, afA, bfA, afB, bfB);  ITER(11, afB, bfB, afA, bfA);
    ITER(12, afA, bfA, afB, bfB);  ITER(13, afB, bfB, afA, bfA);
    ITER(14, afA, bfA, afB, bfB);  ITER(15, afB, bfB, afA, bfA);
    ITER(16, afA, bfA, afB, bfB);  ITER(17, afB, bfB, afA, bfA);
    ITER(18, afA, bfA, afB, bfB);  ITER(19, afB, bfB, afA, bfA);
    ITER(20, afA, bfA, afB, bfB);  ITER(21, afB, bfB, afA, bfA);
    ITER(22, afA, bfA, afB, bfB);  ITER(23, afB, bfB, afA, bfA);
    ITER(24, afA, bfA, afB, bfB);  ITER(25, afB, bfB, afA, bfA);
    ITER(26, afA, bfA, afB, bfB);  ITER(27, afB, bfB, afA, bfA);
    ITER(28, afA, bfA, afB, bfB);  ITER(29, afB, bfB, afA, bfA);
    ITER(30, afA, bfA, afB, bfB);  ITER(31, afB, bfB, afA, bfA);

    // ---------------- epilogue (C values scaled x16; score is scale-invariant) ----------------
    unsigned short* Y = (unsigned short*)smem;
    const int YP = 264;   // padded cols

    // chunk A: C rows 0..129
    if (wr == 0) {
        #pragma unroll
        for (int m = 0; m < 8; ++m) {
            int rbase = m * 16 + lgrp * 4;
            #pragma unroll
            for (int n = 0; n < 4; ++n) {
                int col = wc * 64 + n * 16 + lrow;
                #pragma unroll
                for (int j = 0; j < 4; ++j)
                    Y[(rbase + j) * YP + col] = f2bf(acc[m][n][j]);
            }
        }
    } else if (lgrp == 0) {   // rows 128,129 from wr=1, m=0, j=0,1
        #pragma unroll
        for (int n = 0; n < 4; ++n) {
            int col = wc * 64 + n * 16 + lrow;
            #pragma unroll
            for (int j = 0; j < 2; ++j)
                Y[(128 + j) * YP + col] = f2bf(acc[0][n][j]);
        }
    }
    __syncthreads();

    // dump C rows 0,1 (slots 0,1)
    if (t < 256) {
        int rr = t >> 7, cc = (t & 127) * 2;
        ushort2 v;
        v.x = Y[rr * YP + cc]; v.y = Y[rr * YP + cc + 1];
        *(ushort2*)(ybnd + ((size_t)((b * 16 + mt) * 4 + rr)) * 1024 + bn * 256 + cc) = v;
    }
    // reduce rows 0..127
    {
        int r = t >> 2, q = t & 3;
        const unsigned short* y0 = Y + r * YP + q * 64;
        float sn = 0.f, sc = 0.f;
        #pragma unroll
        for (int c8 = 0; c8 < 8; ++c8) {
            short8 v0 = *(const short8*)(y0 + c8 * 8);
            short8 v1 = *(const short8*)(y0 + YP + c8 * 8);
            short8 v2 = *(const short8*)(y0 + 2 * YP + c8 * 8);
            #pragma unroll
            for (int j = 0; j < 8; ++j) {
                float f0 = bf2f((unsigned short)v0[j]);
                float f1 = bf2f((unsigned short)v1[j]);
                float f2 = bf2f((unsigned short)v2[j]);
                float d0 = f1 - f0, d1 = f2 - f1;
                sn += d0 * d0; sc += d0 * d1;
            }
        }
        sn += __shfl_xor(sn, 1); sn += __shfl_xor(sn, 2);
        sc += __shfl_xor(sc, 1); sc += __shfl_xor(sc, 2);
        if (q == 0) {
            size_t o = ((size_t)b * SS + m0 + r) * 4 + bn;
            pn[o] = sn; pc[o] = sc;
        }
    }
    __syncthreads();

    // chunk B: C rows 128..255 -> LDS rows 0..127
    if (wr == 1) {
        #pragma unroll
        for (int m = 0; m < 8; ++m) {
            int rbase = m * 16 + lgrp * 4;
            #pragma unroll
            for (int n = 0; n < 4; ++n) {
                int col = wc * 64 + n * 16 + lrow;
                #pragma unroll
                for (int j = 0; j < 4; ++j)
                    Y[(rbase + j) * YP + col] = f2bf(acc[m][n][j]);
            }
        }
    }
    __syncthreads();

    // dump C rows 254,255 (LDS rows 126,127 -> slots 2,3)
    if (t < 256) {
        int rr = t >> 7, cc = (t & 127) * 2;
        ushort2 v;
        v.x = Y[(126 + rr) * YP + cc]; v.y = Y[(126 + rr) * YP + cc + 1];
        *(ushort2*)(ybnd + ((size_t)((b * 16 + mt) * 4 + 2 + rr)) * 1024 + bn * 256 + cc) = v;
    }
    // reduce rows 128..254
    {
        int r2 = t >> 2, q = t & 3;
        float sn = 0.f, sc = 0.f;
        if (r2 <= 126) {
            const unsigned short* y0 = Y + r2 * YP + q * 64;
            int rc = (r2 < 126) ? 2 : 1;
            #pragma unroll
            for (int c8 = 0; c8 < 8; ++c8) {
                short8 v0 = *(const short8*)(y0 + c8 * 8);
                short8 v1 = *(const short8*)(y0 + YP + c8 * 8);
                short8 v2 = *(const short8*)(y0 + rc * YP + c8 * 8);
                #pragma unroll
                for (int j = 0; j < 8; ++j) {
                    float f0 = bf2f((unsigned short)v0[j]);
                    float f1 = bf2f((unsigned short)v1[j]);
                    float f2 = bf2f((unsigned short)v2[j]);
                    float d0 = f1 - f0, d1 = f2 - f1;
                    sn += d0 * d0; sc += d0 * d1;
                }
            }
        }
        sn += __shfl_xor(sn, 1); sn += __shfl_xor(sn, 2);
        sc += __shfl_xor(sc, 1); sc += __shfl_xor(sc, 2);
        if (q == 0 && r2 <= 126) {
            size_t o = ((size_t)b * SS + m0 + 128 + r2) * 4 + bn;
            pn[o] = sn;
            if (r2 <= 125) pc[o] = sc;
        }
    }
}

// ---- pass 2: cross-tile boundary scores from dumped rows ----
__global__ void bnd_k(const unsigned short* __restrict__ ybnd,
                      float* __restrict__ pn, float* __restrict__ pc) {
    int b = blockIdx.x / 15, mt = blockIdx.x % 15;
    const unsigned short* T0 = ybnd + ((size_t)(b * 16 + mt) * 4) * 1024;
    const unsigned short* T1 = T0 + 4 * 1024;
    int l = threadIdx.x;
    float n255 = 0.f, c254 = 0.f, c255 = 0.f;
    #pragma unroll
    for (int k = 0; k < 16; ++k) {
        int c = l * 16 + k;
        float s2 = bf2f(T0[2 * 1024 + c]);
        float s3 = bf2f(T0[3 * 1024 + c]);
        float u0 = bf2f(T1[0 * 1024 + c]);
        float u1 = bf2f(T1[1 * 1024 + c]);
        float d254 = s3 - s2, d255 = u0 - s3, d256 = u1 - u0;
        n255 += d255 * d255; c254 += d254 * d255; c255 += d255 * d256;
    }
    #pragma unroll
    for (int off = 32; off > 0; off >>= 1) {
        n255 += __shfl_down(n255, off);
        c254 += __shfl_down(c254, off);
        c255 += __shfl_down(c255, off);
    }
    if (l == 0) {
        int i255 = mt * 256 + 255;
        float4 vn = {n255, 0.f, 0.f, 0.f};
        float4 va = {c254, 0.f, 0.f, 0.f};
        float4 vb = {c255, 0.f, 0.f, 0.f};
        *(float4*)(pn + ((size_t)b * SS + i255) * 4) = vn;
        *(float4*)(pc + ((size_t)b * SS + i255 - 1) * 4) = va;
        *(float4*)(pc + ((size_t)b * SS + i255) * 4) = vb;
    }
}

// ---- pass 3: combine partials -> scores -> adj (scale-invariant) ----
__global__ void score_k(const float* __restrict__ pn, const float* __restrict__ pc,
                        const float* __restrict__ gate, float* __restrict__ out) {
    int tid = blockIdx.x * 256 + threadIdx.x;
    if (tid >= NB * NI) return;
    int b = tid / NI;
    int i = tid - b * NI;
    size_t base = ((size_t)b * SS + i) * 4;
    float n0 = 0.f, n1 = 0.f, c0 = 0.f;
    #pragma unroll
    for (int j = 0; j < 4; ++j) {
        n0 += pn[base + j];
        n1 += pn[base + 4 + j];
        c0 += pc[base + j];
    }
    float d1a = sqrtf(fmaxf(n0, 0.f));
    float d1b = sqrtf(fmaxf(n1, 0.f));
    float d2  = sqrtf(fmaxf(n0 + 2.f * c0 + n1, 0.f));
    float s = fmaxf(1.f - (d1a + d1b - d2) / fmaxf(d2, 1e-6f), 0.f);
    float g = gate[0] * 0.5f;
    out[(size_t)b * SS + i + 1] = g * (s * (1.f / (float)NI) - 0.5f) * 0.1f;
    if (i == 0) {
        float e = g * (-0.5f) * 0.1f;
        out[(size_t)b * SS] = e;
        out[(size_t)b * SS + SS - 1] = e;
    }
}

extern "C" void kernel_launch(void* const* d_in, const int* in_sizes, int n_in,
                              void* d_out, int out_size, void* d_ws, size_t ws_size,
                              hipStream_t stream) {
    const float* x    = (const float*)d_in[0];
    const float* W    = (const float*)d_in[1];
    // d_in[2] (bias) cancels in all distances -> unused
    const float* gate = (const float*)d_in[3];
    float* out = (float*)d_out;
    char* ws = (char*)d_ws;

    unsigned char*  Wb   = (unsigned char*)(ws + WB_OFF);
    unsigned char*  xb   = (unsigned char*)(ws + XB_OFF);
    unsigned short* ybnd = (unsigned short*)(ws + YB_OFF);
    float* pn = (float*)(ws + PN_OFF);
    float* pc = (float*)(ws + PC_OFF);

    conv_all<<<16896, 256, 0, stream>>>(x, W, xb, Wb);
    gemm_nc<<<512, 512, 0, stream>>>(xb, Wb, pn, pc, ybnd);
    bnd_k<<<NB * 15, 64, 0, stream>>>(ybnd, pn, pc);
    score_k<<<(NB * NI + 255) / 256, 256, 0, stream>>>(pn, pc, gate, out);
}